// Round 5
// baseline (142.507 us; speedup 1.0000x reference)
//
#include <hip/hip_runtime.h>
#include <hip/hip_bf16.h>
#include <math.h>

// ---------------------------------------------------------------------------
// HybridClassifier, fused, MFMA quantum filter, occupancy-tuned:
//   K0: w1 -> bf16 [128][800] (zero-padded)
//   K1 (mega), 8 batch rows per block, grid 1024, 21.1 KB LDS -> 7 blocks/CU:
//     phase A: psi (VALU trig) -> wave-private LDS -> phi^T = U*psi^T via
//              16x16x32 bf16 MFMA (U in regs; K-pad zeros synthesized in
//              registers, not LDS) -> WHT sign-reduce (shfl_xor) -> feats
//              bf16 in LDS [8][808]
//     phase B: fc1 = relu(feats @ w1B^T + b1) via MFMA -> h1 LDS (aliases psi)
//     phase D: fc2+relu, fc3, analytic head -> out
// ---------------------------------------------------------------------------

#define BATCH   8192
#define NPATCH  196
#define ROWS    8
#define NITEMS  (ROWS * NPATCH)   // 1568
#define KPAD    800
#define FLD     808
#define H1LD    132

typedef __attribute__((ext_vector_type(8))) short bfrag;
typedef __attribute__((ext_vector_type(4))) float f32x4;

static __device__ __forceinline__ unsigned short f2bf(float f) {
    __hip_bfloat16 h = __float2bfloat16(f);
    return __builtin_bit_cast(unsigned short, h);
}
static __device__ __forceinline__ unsigned int pkbf(float lo, float hi) {
    return ((unsigned int)f2bf(hi) << 16) | (unsigned int)f2bf(lo);
}

// ===========================================================================
// K0: w1 (fp32 [120][784]) -> bf16 [128][800], zero-padded.
// ===========================================================================
__global__ __launch_bounds__(256) void w1prep_kernel(
    const float* __restrict__ w1, unsigned short* __restrict__ w1B)
{
    int t = blockIdx.x * 256 + threadIdx.x;
    if (t >= 128 * KPAD) return;
    int n = t / KPAD;
    int k = t - n * KPAD;
    float v = (n < 120 && k < 784) ? w1[n * 784 + k] : 0.f;
    w1B[t] = f2bf(v);
}

// ===========================================================================
// K1: mega kernel. Grid 1024 x 256 threads; block = batch rows m0..m0+7.
// LDS: featsL (12928 B) + pool (8192 B) = 21120 B -> 7 blocks/CU.
// pool holds psiL[4][64][16] in phase A, then h1L/h2L in phases B/D
// (lifetimes disjoint across the phase A->B __syncthreads).
// ===========================================================================
__global__ __launch_bounds__(256, 7) void mega_kernel(
    const float* __restrict__ x, const float* __restrict__ U,
    const unsigned short* __restrict__ w1B,
    const float* __restrict__ b1,
    const float* __restrict__ w2, const float* __restrict__ b2,
    const float* __restrict__ w3, const float* __restrict__ b3,
    float* __restrict__ out)
{
    __shared__ __align__(16) unsigned short featsL[ROWS * FLD];  // 12928 B
    __shared__ __align__(16) unsigned char pool[8192];           //  8192 B

    // phase A view: psiL[wave][lane][16] bf16
    unsigned short (*psiL)[64][16] =
        reinterpret_cast<unsigned short (*)[64][16]>(pool);
    // phase B/D views (alias psiL; valid after the A->B barrier)
    float* h1L = reinterpret_cast<float*>(pool);                 // [8][132]
    float* h2L = reinterpret_cast<float*>(pool + ROWS * H1LD * 4); // [8][84]

    const int tid  = threadIdx.x;
    const int lane = tid & 63;
    const int wv   = tid >> 6;
    const int lrow = lane & 15;
    const int lgrp = lane >> 4;
    const int m0   = blockIdx.x * ROWS;

    // zero feats K-pad tail (cols 784..799)
    if (tid < ROWS * 16)
        featsL[(tid >> 4) * FLD + 784 + (tid & 15)] = 0;

    // U as MFMA A-frag, loaded ONCE: A[row=lrow][k=8*lgrp+j], zero for k>=16
    bfrag Uf;
    {
        union { bfrag f; unsigned int u[4]; } uu;
        if (lgrp < 2) {
            float4 a = *reinterpret_cast<const float4*>(U + lrow * 16 + lgrp * 8);
            float4 b = *reinterpret_cast<const float4*>(U + lrow * 16 + lgrp * 8 + 4);
            uu.u[0] = pkbf(a.x, a.y); uu.u[1] = pkbf(a.z, a.w);
            uu.u[2] = pkbf(b.x, b.y); uu.u[3] = pkbf(b.z, b.w);
        } else {
            uu.u[0] = uu.u[1] = uu.u[2] = uu.u[3] = 0u;
        }
        Uf = uu.f;
    }

    // ---- phase A: 25 chunks of 64 items, round-robined over 4 waves ----
    for (int c = wv; c < (NITEMS + 63) / 64; c += 4) {
        int item = c * 64 + lane;
        int it   = item < NITEMS - 1 ? item : NITEMS - 1;   // clamp tail
        int r  = it / NPATCH;
        int p  = it - r * NPATCH;
        int pr = p / 14;
        int pc = p - pr * 14;
        const float* xr = x + (size_t)(m0 + r) * 784 + pr * 56 + pc * 2;
        float2 xa = *reinterpret_cast<const float2*>(xr);
        float2 xb = *reinterpret_cast<const float2*>(xr + 28);

        float s0 = __sinf(0.5f * xa.x), c0 = __cosf(0.5f * xa.x);
        float s1 = __sinf(0.5f * xa.y), c1 = __cosf(0.5f * xa.y);
        float s2 = __sinf(0.5f * xb.x), c2 = __cosf(0.5f * xb.x);
        float s3 = __sinf(0.5f * xb.y), c3 = __cosf(0.5f * xb.y);

        float t01[4] = {c0 * c1, c0 * s1, s0 * c1, s0 * s1};
        float t23[4] = {c2 * c3, c2 * s3, s2 * c3, s2 * s3};

        unsigned int pw[8];
#pragma unroll
        for (int q = 0; q < 8; ++q) {
            float plo = t01[(2 * q) >> 2]     * t23[(2 * q) & 3];
            float phv = t01[(2 * q + 1) >> 2] * t23[(2 * q + 1) & 3];
            pw[q] = pkbf(plo, phv);
        }
        *reinterpret_cast<uint4*>(&psiL[wv][lane][0]) =
            make_uint4(pw[0], pw[1], pw[2], pw[3]);
        *reinterpret_cast<uint4*>(&psiL[wv][lane][8]) =
            make_uint4(pw[4], pw[5], pw[6], pw[7]);

        // 4 sub-tiles of 16 items: phi^T = U * psi^T, then WHT sign-reduce
#pragma unroll
        for (int sub = 0; sub < 4; ++sub) {
            bfrag Bf = {};
            if (lgrp < 2)   // k >= 16 is zero-pad, synthesized in regs
                Bf = *reinterpret_cast<const bfrag*>(
                    &psiL[wv][sub * 16 + lrow][lgrp * 8]);
            f32x4 dz = {0.f, 0.f, 0.f, 0.f};
            f32x4 d = __builtin_amdgcn_mfma_f32_16x16x32_bf16(Uf, Bf, dz, 0, 0, 0);
            // lane: phi[i = 4*lgrp + reg][item = sub*16 + lrow]
            float q0 = d[0] * d[0], q1 = d[1] * d[1];
            float q2 = d[2] * d[2], q3 = d[3] * d[3];
            float sAll = (q0 + q1) + (q2 + q3);        // for w0, w1 (bits of lgrp)
            float uu2  = (q0 + q1) - (q2 + q3);        // w2: bit1 = reg>>1
            float vv2  = (q0 - q1) + (q2 - q3);        // w3: bit0 = reg&1
            float t    = __shfl_xor(sAll, 16);
            float Aa   = sAll + t;
            float Bb   = (lane & 16) ? (t - sAll) : (sAll - t);
            t = __shfl_xor(Aa, 32);
            float mw0 = (lane & 32) ? (t - Aa) : (Aa - t);   // sign by bit3
            float mw1 = Bb + __shfl_xor(Bb, 32);             // sign by bit2
            float u16 = uu2 + __shfl_xor(uu2, 16);
            float mw2 = u16 + __shfl_xor(u16, 32);
            float v16 = vv2 + __shfl_xor(vv2, 16);
            float mw3 = v16 + __shfl_xor(v16, 32);

            int item16 = c * 64 + sub * 16 + lrow;
            if (lgrp == 0 && item16 < NITEMS) {
                int rr = item16 / NPATCH;
                int pp = item16 - rr * NPATCH;
                ushort4 o;
                o.x = f2bf(mw0); o.y = f2bf(mw1);
                o.z = f2bf(mw2); o.w = f2bf(mw3);
                *reinterpret_cast<ushort4*>(&featsL[rr * FLD + pp * 4]) = o;
            }
        }
    }
    __syncthreads();
    // ---- psiL is dead from here; pool is now h1L/h2L ----

    // ---- phase B: fc1 MFMA. wave wv -> cols [wv*32, wv*32+32) ----
    {
        const unsigned short* fA = &featsL[(lrow & 7) * FLD + lgrp * 8];
        const unsigned short* bp0 =
            w1B + (size_t)(wv * 32 + lrow) * KPAD + lgrp * 8;
        const unsigned short* bp1 = bp0 + 16 * KPAD;

        f32x4 acc0 = {}, acc1 = {};
        for (int k0 = 0; k0 < KPAD; k0 += 32) {
            bfrag a   = *reinterpret_cast<const bfrag*>(fA + k0);
            bfrag b0  = *reinterpret_cast<const bfrag*>(bp0 + k0);
            bfrag b1f = *reinterpret_cast<const bfrag*>(bp1 + k0);
            acc0 = __builtin_amdgcn_mfma_f32_16x16x32_bf16(a, b0, acc0, 0, 0, 0);
            acc1 = __builtin_amdgcn_mfma_f32_16x16x32_bf16(a, b1f, acc1, 0, 0, 0);
        }
        f32x4 accs[2] = {acc0, acc1};
#pragma unroll
        for (int nj = 0; nj < 2; ++nj) {
            int col = wv * 32 + nj * 16 + lrow;
            if (col < 120) {
                float bias = b1[col];
#pragma unroll
                for (int rr2 = 0; rr2 < 4; ++rr2) {
                    int row = lgrp * 4 + rr2;   // D rows 8-15 duplicate 0-7
                    if (row < ROWS)
                        h1L[row * H1LD + col] =
                            fmaxf(accs[nj][rr2] + bias, 0.f);
                }
            }
        }
    }
    __syncthreads();

    // ---- phase D: fc2+relu (8 x 84 -> 168 col-quad items) ----
    for (int e = tid; e < ROWS * 21; e += 256) {
        int r  = e / 21;
        int nq = e - r * 21;
        int n0 = nq * 4;
        float4 bias = *reinterpret_cast<const float4*>(b2 + n0);
        float accv[4] = {bias.x, bias.y, bias.z, bias.w};
#pragma unroll
        for (int kq = 0; kq < 30; ++kq) {
            float4 a = *reinterpret_cast<const float4*>(&h1L[r * H1LD + kq * 4]);
#pragma unroll
            for (int nn = 0; nn < 4; ++nn) {
                const float4 wvv = *reinterpret_cast<const float4*>(
                    w2 + (size_t)(n0 + nn) * 120 + kq * 4);
                accv[nn] = fmaf(a.x, wvv.x, accv[nn]);
                accv[nn] = fmaf(a.y, wvv.y, accv[nn]);
                accv[nn] = fmaf(a.z, wvv.z, accv[nn]);
                accv[nn] = fmaf(a.w, wvv.w, accv[nn]);
            }
        }
        float4 o;
        o.x = fmaxf(accv[0], 0.f);
        o.y = fmaxf(accv[1], 0.f);
        o.z = fmaxf(accv[2], 0.f);
        o.w = fmaxf(accv[3], 0.f);
        *reinterpret_cast<float4*>(&h2L[r * 84 + n0]) = o;
    }
    __syncthreads();

    // ---- fc3 + head, one thread per row ----
    if (tid < ROWS) {
        int r = tid;
        float acc = b3[0];
#pragma unroll
        for (int kq = 0; kq < 21; ++kq) {
            float4 a   = *reinterpret_cast<const float4*>(&h2L[r * 84 + kq * 4]);
            float4 wvv = *reinterpret_cast<const float4*>(w3 + kq * 4);
            acc = fmaf(a.x, wvv.x, acc);
            acc = fmaf(a.y, wvv.y, acc);
            acc = fmaf(a.z, wvv.z, acc);
            acc = fmaf(a.w, wvv.w, acc);
        }
        float ev = 0.5f * (1.0f + __sinf(acc));
        float pp = 1.0f / (1.0f + __expf(-ev));
        out[m0 + r]         = pp;
        out[BATCH + m0 + r] = 1.0f - pp;
    }
}

// ===========================================================================
extern "C" void kernel_launch(void* const* d_in, const int* in_sizes, int n_in,
                              void* d_out, int out_size, void* d_ws, size_t ws_size,
                              hipStream_t stream)
{
    (void)in_sizes; (void)n_in; (void)out_size; (void)ws_size;
    const float* x  = (const float*)d_in[0];
    const float* U  = (const float*)d_in[1];
    const float* w1 = (const float*)d_in[2];
    const float* b1 = (const float*)d_in[3];
    const float* w2 = (const float*)d_in[4];
    const float* b2 = (const float*)d_in[5];
    const float* w3 = (const float*)d_in[6];
    const float* b3 = (const float*)d_in[7];
    float* out = (float*)d_out;

    unsigned short* w1B = (unsigned short*)d_ws;   // 128*800 bf16 = 205 KB

    w1prep_kernel<<<dim3((128 * KPAD + 255) / 256), dim3(256), 0, stream>>>(w1, w1B);
    mega_kernel<<<dim3(BATCH / ROWS), dim3(256), 0, stream>>>(
        x, U, w1B, b1, w2, b2, w3, b3, out);
}

// Round 6
// 135.979 us; speedup vs baseline: 1.0480x; 1.0480x over previous
//
#include <hip/hip_runtime.h>
#include <hip/hip_bf16.h>
#include <math.h>

// ---------------------------------------------------------------------------
// HybridClassifier, fused, double-MFMA quantum filter:
//   K0: w1 -> bf16 [128][800] (zero-padded)
//   K1 (mega), 8 batch rows per block, grid 1024:
//     phase A: psi (VALU trig) -> wave-private LDS -> phi^T = U*psi^T via
//              16x16x16 bf16 MFMA -> square+pack -> meas = Z*q via a second
//              16x16x16 MFMA (C/D layout == B layout, zero cross-lane ops)
//              -> feats bf16 in LDS [8][808]
//     phase B: fc1 = relu(feats @ w1B^T + b1) via 16x16x32 MFMA -> h1 LDS
//     phase D: fc2+relu, fc3, analytic head -> out
// ---------------------------------------------------------------------------

#define BATCH   8192
#define NPATCH  196
#define ROWS    8
#define NITEMS  (ROWS * NPATCH)   // 1568
#define KPAD    800
#define FLD     808
#define H1LD    132

typedef __attribute__((ext_vector_type(8))) short bfrag;    // 8 bf16 (x32 MFMA)
typedef __attribute__((ext_vector_type(4))) short bfrag4;   // 4 bf16 (x16 MFMA)
typedef __attribute__((ext_vector_type(4))) float f32x4;

#if __has_builtin(__builtin_amdgcn_mfma_f32_16x16x16bf16_1k)
#define USE_X16 1
#else
#define USE_X16 0
#endif

static __device__ __forceinline__ unsigned short f2bf(float f) {
    __hip_bfloat16 h = __float2bfloat16(f);
    return __builtin_bit_cast(unsigned short, h);
}
static __device__ __forceinline__ unsigned int pkbf(float lo, float hi) {
    return ((unsigned int)f2bf(hi) << 16) | (unsigned int)f2bf(lo);
}

// ===========================================================================
// K0: w1 (fp32 [120][784]) -> bf16 [128][800], zero-padded.
// ===========================================================================
__global__ __launch_bounds__(256) void w1prep_kernel(
    const float* __restrict__ w1, unsigned short* __restrict__ w1B)
{
    int t = blockIdx.x * 256 + threadIdx.x;
    if (t >= 128 * KPAD) return;
    int n = t / KPAD;
    int k = t - n * KPAD;
    float v = (n < 120 && k < 784) ? w1[n * 784 + k] : 0.f;
    w1B[t] = f2bf(v);
}

// ===========================================================================
// K1: mega kernel. Grid 1024 x 256 threads; block = batch rows m0..m0+7.
// LDS: featsL (12928 B) + pool (8192 B) = 21120 B.
// pool holds psiL[4][64][16] in phase A, then h1L/h2L in phases B/D.
// ===========================================================================
__global__ __launch_bounds__(256, 4) void mega_kernel(
    const float* __restrict__ x, const float* __restrict__ U,
    const unsigned short* __restrict__ w1B,
    const float* __restrict__ b1,
    const float* __restrict__ w2, const float* __restrict__ b2,
    const float* __restrict__ w3, const float* __restrict__ b3,
    float* __restrict__ out)
{
    __shared__ __align__(16) unsigned short featsL[ROWS * FLD];  // 12928 B
    __shared__ __align__(16) unsigned char pool[8192];           //  8192 B

    unsigned short (*psiL)[64][16] =
        reinterpret_cast<unsigned short (*)[64][16]>(pool);
    float* h1L = reinterpret_cast<float*>(pool);                   // [8][132]
    float* h2L = reinterpret_cast<float*>(pool + ROWS * H1LD * 4); // [8][84]

    const int tid  = threadIdx.x;
    const int lane = tid & 63;
    const int wv   = tid >> 6;
    const int lrow = lane & 15;
    const int lgrp = lane >> 4;
    const int m0   = blockIdx.x * ROWS;

    // zero feats K-pad tail (cols 784..799)
    if (tid < ROWS * 16)
        featsL[(tid >> 4) * FLD + 784 + (tid & 15)] = 0;

#if USE_X16
    // U as 16x16x16 A-frag: A[row=lrow][k=4*lgrp+j], loaded once (2 VGPR)
    bfrag4 Uf16;
    {
        union { bfrag4 f; unsigned int u[2]; } uu;
        float4 a = *reinterpret_cast<const float4*>(U + lrow * 16 + lgrp * 4);
        uu.u[0] = pkbf(a.x, a.y);
        uu.u[1] = pkbf(a.z, a.w);
        Uf16 = uu.f;
    }
    // PauliZ sign matrix as A-frag: A[row=w][k=i] = 1-2*bit_{3-w}(i), rows>=4: 0
    bfrag4 Zf;
    {
        union { bfrag4 f; unsigned int u[2]; } zz;
        if (lrow < 4) {
            float z[4];
#pragma unroll
            for (int j = 0; j < 4; ++j) {
                int k = 4 * lgrp + j;
                z[j] = ((k >> (3 - lrow)) & 1) ? -1.f : 1.f;
            }
            zz.u[0] = pkbf(z[0], z[1]);
            zz.u[1] = pkbf(z[2], z[3]);
        } else {
            zz.u[0] = zz.u[1] = 0u;
        }
        Zf = zz.f;
    }
#else
    // x32 U-frag fallback: A[row=lrow][k=8*lgrp+j], zero for k>=16
    bfrag Uf;
    {
        union { bfrag f; unsigned int u[4]; } uu;
        if (lgrp < 2) {
            float4 a = *reinterpret_cast<const float4*>(U + lrow * 16 + lgrp * 8);
            float4 b = *reinterpret_cast<const float4*>(U + lrow * 16 + lgrp * 8 + 4);
            uu.u[0] = pkbf(a.x, a.y); uu.u[1] = pkbf(a.z, a.w);
            uu.u[2] = pkbf(b.x, b.y); uu.u[3] = pkbf(b.z, b.w);
        } else {
            uu.u[0] = uu.u[1] = uu.u[2] = uu.u[3] = 0u;
        }
        Uf = uu.f;
    }
#endif

    // ---- phase A: 25 chunks of 64 items, round-robined over 4 waves ----
    for (int c = wv; c < (NITEMS + 63) / 64; c += 4) {
        int item = c * 64 + lane;
        int it   = item < NITEMS - 1 ? item : NITEMS - 1;   // clamp tail
        int r  = it / NPATCH;
        int p  = it - r * NPATCH;
        int pr = p / 14;
        int pc = p - pr * 14;
        const float* xr = x + (size_t)(m0 + r) * 784 + pr * 56 + pc * 2;
        float2 xa = *reinterpret_cast<const float2*>(xr);
        float2 xb = *reinterpret_cast<const float2*>(xr + 28);

        float s0, c0, s1, c1, s2, c2, s3, c3;
        __sincosf(0.5f * xa.x, &s0, &c0);
        __sincosf(0.5f * xa.y, &s1, &c1);
        __sincosf(0.5f * xb.x, &s2, &c2);
        __sincosf(0.5f * xb.y, &s3, &c3);

        float t01[4] = {c0 * c1, c0 * s1, s0 * c1, s0 * s1};
        float t23[4] = {c2 * c3, c2 * s3, s2 * c3, s2 * s3};

        unsigned int pw[8];
#pragma unroll
        for (int q = 0; q < 8; ++q) {
            float plo = t01[(2 * q) >> 2]     * t23[(2 * q) & 3];
            float phv = t01[(2 * q + 1) >> 2] * t23[(2 * q + 1) & 3];
            pw[q] = pkbf(plo, phv);
        }
        *reinterpret_cast<uint4*>(&psiL[wv][lane][0]) =
            make_uint4(pw[0], pw[1], pw[2], pw[3]);
        *reinterpret_cast<uint4*>(&psiL[wv][lane][8]) =
            make_uint4(pw[4], pw[5], pw[6], pw[7]);

        // 4 sub-tiles of 16 items
#pragma unroll
        for (int sub = 0; sub < 4; ++sub) {
            int item16 = c * 64 + sub * 16 + lrow;
#if USE_X16
            // B-frag: psi[k=4*lgrp+j][col=item]
            bfrag4 Pf = *reinterpret_cast<const bfrag4*>(
                &psiL[wv][sub * 16 + lrow][lgrp * 4]);
            f32x4 dz = {0.f, 0.f, 0.f, 0.f};
            f32x4 d = __builtin_amdgcn_mfma_f32_16x16x16bf16_1k(
                Uf16, Pf, dz, 0, 0, 0);
            // q as B-frag for the Z-MFMA: C/D layout == B layout (k=4*lgrp+reg)
            union { bfrag4 f; unsigned int u[2]; } qq;
            qq.u[0] = pkbf(d[0] * d[0], d[1] * d[1]);
            qq.u[1] = pkbf(d[2] * d[2], d[3] * d[3]);
            f32x4 m = __builtin_amdgcn_mfma_f32_16x16x16bf16_1k(
                Zf, qq.f, dz, 0, 0, 0);
            if (lgrp == 0 && item16 < NITEMS) {
                int rr = item16 / NPATCH;
                int pp = item16 - rr * NPATCH;
                uint2 o2;
                o2.x = pkbf(m[0], m[1]);   // w0, w1
                o2.y = pkbf(m[2], m[3]);   // w2, w3
                *reinterpret_cast<uint2*>(&featsL[rr * FLD + pp * 4]) = o2;
            }
#else
            bfrag Bf = {};
            if (lgrp < 2)
                Bf = *reinterpret_cast<const bfrag*>(
                    &psiL[wv][sub * 16 + lrow][lgrp * 8]);
            f32x4 dz = {0.f, 0.f, 0.f, 0.f};
            f32x4 d = __builtin_amdgcn_mfma_f32_16x16x32_bf16(Uf, Bf, dz, 0, 0, 0);
            float q0 = d[0] * d[0], q1 = d[1] * d[1];
            float q2 = d[2] * d[2], q3 = d[3] * d[3];
            float sAll = (q0 + q1) + (q2 + q3);
            float uu2  = (q0 + q1) - (q2 + q3);
            float vv2  = (q0 - q1) + (q2 - q3);
            float t    = __shfl_xor(sAll, 16);
            float Aa   = sAll + t;
            float Bb   = (lane & 16) ? (t - sAll) : (sAll - t);
            t = __shfl_xor(Aa, 32);
            float mw0 = (lane & 32) ? (t - Aa) : (Aa - t);
            float mw1 = Bb + __shfl_xor(Bb, 32);
            float u16 = uu2 + __shfl_xor(uu2, 16);
            float mw2 = u16 + __shfl_xor(u16, 32);
            float v16 = vv2 + __shfl_xor(vv2, 16);
            float mw3 = v16 + __shfl_xor(v16, 32);
            if (lgrp == 0 && item16 < NITEMS) {
                int rr = item16 / NPATCH;
                int pp = item16 - rr * NPATCH;
                ushort4 o;
                o.x = f2bf(mw0); o.y = f2bf(mw1);
                o.z = f2bf(mw2); o.w = f2bf(mw3);
                *reinterpret_cast<ushort4*>(&featsL[rr * FLD + pp * 4]) = o;
            }
#endif
        }
    }
    __syncthreads();
    // ---- psiL is dead from here; pool is now h1L/h2L ----

    // ---- phase B: fc1 MFMA. wave wv -> cols [wv*32, wv*32+32) ----
    {
        const unsigned short* fA = &featsL[(lrow & 7) * FLD + lgrp * 8];
        const unsigned short* bp0 =
            w1B + (size_t)(wv * 32 + lrow) * KPAD + lgrp * 8;
        const unsigned short* bp1 = bp0 + 16 * KPAD;

        f32x4 acc0 = {}, acc1 = {};
        for (int k0 = 0; k0 < KPAD; k0 += 32) {
            bfrag a   = *reinterpret_cast<const bfrag*>(fA + k0);
            bfrag b0  = *reinterpret_cast<const bfrag*>(bp0 + k0);
            bfrag b1f = *reinterpret_cast<const bfrag*>(bp1 + k0);
            acc0 = __builtin_amdgcn_mfma_f32_16x16x32_bf16(a, b0, acc0, 0, 0, 0);
            acc1 = __builtin_amdgcn_mfma_f32_16x16x32_bf16(a, b1f, acc1, 0, 0, 0);
        }
        f32x4 accs[2] = {acc0, acc1};
#pragma unroll
        for (int nj = 0; nj < 2; ++nj) {
            int col = wv * 32 + nj * 16 + lrow;
            if (col < 120) {
                float bias = b1[col];
#pragma unroll
                for (int rr2 = 0; rr2 < 4; ++rr2) {
                    int row = lgrp * 4 + rr2;   // D rows 8-15 duplicate 0-7
                    if (row < ROWS)
                        h1L[row * H1LD + col] =
                            fmaxf(accs[nj][rr2] + bias, 0.f);
                }
            }
        }
    }
    __syncthreads();

    // ---- phase D: fc2+relu (8 x 84 -> 168 col-quad items) ----
    for (int e = tid; e < ROWS * 21; e += 256) {
        int r  = e / 21;
        int nq = e - r * 21;
        int n0 = nq * 4;
        float4 bias = *reinterpret_cast<const float4*>(b2 + n0);
        float accv[4] = {bias.x, bias.y, bias.z, bias.w};
#pragma unroll
        for (int kq = 0; kq < 30; ++kq) {
            float4 a = *reinterpret_cast<const float4*>(&h1L[r * H1LD + kq * 4]);
#pragma unroll
            for (int nn = 0; nn < 4; ++nn) {
                const float4 wvv = *reinterpret_cast<const float4*>(
                    w2 + (size_t)(n0 + nn) * 120 + kq * 4);
                accv[nn] = fmaf(a.x, wvv.x, accv[nn]);
                accv[nn] = fmaf(a.y, wvv.y, accv[nn]);
                accv[nn] = fmaf(a.z, wvv.z, accv[nn]);
                accv[nn] = fmaf(a.w, wvv.w, accv[nn]);
            }
        }
        float4 o;
        o.x = fmaxf(accv[0], 0.f);
        o.y = fmaxf(accv[1], 0.f);
        o.z = fmaxf(accv[2], 0.f);
        o.w = fmaxf(accv[3], 0.f);
        *reinterpret_cast<float4*>(&h2L[r * 84 + n0]) = o;
    }
    __syncthreads();

    // ---- fc3 + head, one thread per row ----
    if (tid < ROWS) {
        int r = tid;
        float acc = b3[0];
#pragma unroll
        for (int kq = 0; kq < 21; ++kq) {
            float4 a   = *reinterpret_cast<const float4*>(&h2L[r * 84 + kq * 4]);
            float4 wvv = *reinterpret_cast<const float4*>(w3 + kq * 4);
            acc = fmaf(a.x, wvv.x, acc);
            acc = fmaf(a.y, wvv.y, acc);
            acc = fmaf(a.z, wvv.z, acc);
            acc = fmaf(a.w, wvv.w, acc);
        }
        float ev = 0.5f * (1.0f + __sinf(acc));
        float pp = 1.0f / (1.0f + __expf(-ev));
        out[m0 + r]         = pp;
        out[BATCH + m0 + r] = 1.0f - pp;
    }
}

// ===========================================================================
extern "C" void kernel_launch(void* const* d_in, const int* in_sizes, int n_in,
                              void* d_out, int out_size, void* d_ws, size_t ws_size,
                              hipStream_t stream)
{
    (void)in_sizes; (void)n_in; (void)out_size; (void)ws_size;
    const float* x  = (const float*)d_in[0];
    const float* U  = (const float*)d_in[1];
    const float* w1 = (const float*)d_in[2];
    const float* b1 = (const float*)d_in[3];
    const float* w2 = (const float*)d_in[4];
    const float* b2 = (const float*)d_in[5];
    const float* w3 = (const float*)d_in[6];
    const float* b3 = (const float*)d_in[7];
    float* out = (float*)d_out;

    unsigned short* w1B = (unsigned short*)d_ws;   // 128*800 bf16 = 205 KB

    w1prep_kernel<<<dim3((128 * KPAD + 255) / 256), dim3(256), 0, stream>>>(w1, w1B);
    mega_kernel<<<dim3(BATCH / ROWS), dim3(256), 0, stream>>>(
        x, U, w1B, b1, w2, b2, w3, b3, out);
}